// Round 16
// baseline (166.816 us; speedup 1.0000x reference)
//
#include <hip/hip_runtime.h>
#include <math.h>

#define BATCH 128
#define LN_EPS 1e-5f

typedef short bf16x8 __attribute__((ext_vector_type(8)));
typedef short bf16x4 __attribute__((ext_vector_type(4)));
typedef float f32x4  __attribute__((ext_vector_type(4)));

__device__ __forceinline__ ushort f2bf(float f) {
    return __builtin_bit_cast(ushort, (__bf16)f);
}

// tanh via fast exp + HW-approx reciprocal (r13: -9.4us vs IEEE div).
__device__ __forceinline__ float fast_tanh(float v) {
    float e = __expf(2.f * v);
    float r = __builtin_amdgcn_rcpf(e + 1.f);
    return fmaf(-2.f, r, 1.f);
}

__device__ __forceinline__ float fast_rsqrt(float v) {
    return __builtin_amdgcn_rsqf(v);
}

// ---------------------------------------------------------------------------
// prep v2 — unchanged (512 blocks, folded-bias PE tile).
// ---------------------------------------------------------------------------
__global__ __launch_bounds__(256, 2)
void prep_kernel(const float* __restrict__ cw1, const float* __restrict__ cw2,
                 const float* __restrict__ cw3,
                 const float* __restrict__ w3, const float* __restrict__ b3,
                 const float* __restrict__ w5, const float* __restrict__ b5,
                 const float* __restrict__ w7, const float* __restrict__ b7,
                 const float* __restrict__ w9, const float* __restrict__ b9,
                 const float* __restrict__ cb1, const float* __restrict__ cb2,
                 const float* __restrict__ cb3,
                 const float* __restrict__ lg1, const float* __restrict__ lb1,
                 const float* __restrict__ lg2, const float* __restrict__ lb2,
                 ushort* __restrict__ Wm23, ushort* __restrict__ Wm1,
                 float* __restrict__ W0c, float* __restrict__ W3c,
                 float* __restrict__ pe1c,
                 float* __restrict__ cb2t, float* __restrict__ B2k0,
                 float* __restrict__ B2k3,
                 float* __restrict__ cb3t, float* __restrict__ B3k0,
                 float* __restrict__ B3k3) {
    const int tid = threadIdx.x;
    const int bx  = blockIdx.x;              // 512 blocks

    __shared__ float tile[64][12];           // PE+bias window (10 cols used)
    __shared__ float red[4][64][24];         // block-0 composite partials

    if (tid < 64) {
        int idx = bx * 64 + tid;             // 0 .. 32767 exactly
        int s = idx >> 14, r = idx & 16383;
        int j = r & 7, l15 = (r >> 3) & 15, dt = (r >> 7) & 3;
        int quad = (r >> 9) & 3, k2 = (r >> 11) & 1, kk = (r >> 12) & 3;
        int dout = dt * 16 + l15, din = k2 * 32 + quad * 8 + j;
        const float* cw = (s == 0) ? cw2 : cw3;
        const float* lg = (s == 0) ? lg1 : lg2;
        Wm23[idx] = f2bf(cw[dout * 256 + din * 4 + kk] * lg[din]);
    }

    if (bx == 1 && tid < 128) {
        const int s = tid >> 6, ch = tid & 63;
        const float* cw = (s == 0) ? cw2 : cw3;
        const float* lb = (s == 0) ? lb1 : lb2;
        float full = 0.f, k0 = 0.f, k3 = 0.f;
        for (int din = 0; din < 64; ++din) {
            float bv = lb[din];
            const float* wr = cw + ch * 256 + din * 4;
            k0 = fmaf(wr[0], bv, k0);
            k3 = fmaf(wr[3], bv, k3);
            full = fmaf(wr[0] + wr[1] + wr[2] + wr[3], bv, full);
        }
        if (s == 0) { cb2t[ch] = cb2[ch] + full; B2k0[ch] = k0; B2k3[ch] = k3; }
        else        { cb3t[ch] = cb3[ch] + full; B3k0[ch] = k0; B3k3[ch] = k3; }
    }

    if (bx == 0) {
        const int ch = tid & 63, part = tid >> 6;
        const float* cw1row = cw1 + ch * 256;
        float acc[24];
#pragma unroll
        for (int j = 0; j < 24; ++j) acc[j] = 0.f;
        for (int din = part * 16; din < part * 16 + 16; ++din) {
            int ki = din & 3, g = din >> 2;
            float wl[9];
#pragma unroll
            for (int j = 0; j < 9; ++j) wl[j] = 0.f;
            if (ki == 0)      { for (int j = 0; j < 3; ++j) wl[3 + j] = w3[g * 3 + j]; }
            else if (ki == 1) { for (int j = 0; j < 5; ++j) wl[2 + j] = w5[g * 5 + j]; }
            else if (ki == 2) { for (int j = 0; j < 7; ++j) wl[1 + j] = w7[g * 7 + j]; }
            else              { for (int j = 0; j < 9; ++j) wl[j]     = w9[g * 9 + j]; }
#pragma unroll
            for (int kk = 0; kk < 4; ++kk) {
                float c = cw1row[din * 4 + kk];
#pragma unroll
                for (int u = 0; u < 9; ++u) acc[kk + u] += c * wl[u];
            }
            float c0 = cw1row[din * 4 + 0], c3 = cw1row[din * 4 + 3];
#pragma unroll
            for (int u = 0; u < 4; ++u) { acc[16 + u] += c0 * wl[5 + u]; acc[20 + u] += c3 * wl[u]; }
        }
#pragma unroll
        for (int j = 0; j < 24; ++j) red[part][ch][j] = acc[j];
    }

    for (int i = tid; i < 320; i += 256) {
        int d2 = i / 10, pp = i - d2 * 10;
        int p = 8 * bx - 1 + pp;
        int din0 = 2 * d2, g = d2 >> 1;
        float sv = 0.f, cv = 0.f;
        if (p >= 0 && p < 4096) {
            float dv = __expf((float)din0 * -0.14391156831212787f);  // -ln(1e4)/64
            float s, c;
            __sincosf((float)p * dv, &s, &c);
            bool lo = (din0 & 3) == 0;
            sv = s + (lo ? b3[g] : b7[g]);
            cv = c + (lo ? b5[g] : b9[g]);
        }
        tile[din0][pp] = sv;
        tile[din0 + 1][pp] = cv;
    }
    __syncthreads();

    if (bx == 0 && tid < 64) {
        const int ch = tid;
        float w24[24];
#pragma unroll
        for (int j = 0; j < 24; ++j)
            w24[j] = red[0][ch][j] + red[1][ch][j] + red[2][ch][j] + red[3][ch][j];
        int dt = ch >> 4, l15 = ch & 15;
#pragma unroll
        for (int quad = 0; quad < 4; ++quad)
#pragma unroll
            for (int j = 0; j < 8; ++j) {
                int k = quad * 8 + j;
                Wm1[((quad * 4 + dt) * 16 + l15) * 8 + j] = f2bf(k < 12 ? w24[k] : 0.f);
            }
#pragma unroll
        for (int u = 0; u < 4; ++u) { W0c[ch * 4 + u] = w24[16 + u]; W3c[ch * 4 + u] = w24[20 + u]; }
    }

    {
        const int ll = tid >> 6, ch = tid & 63;
        const int l = bx * 4 + ll;
        float acc = cb1[ch];
        const float* cwr = cw1 + ch * 256;
        for (int din = 0; din < 64; ++din) {
            float4 w = *(const float4*)(cwr + din * 4);
            acc = fmaf(w.x, tile[din][2 * ll + 0],
                  fmaf(w.y, tile[din][2 * ll + 1],
                  fmaf(w.z, tile[din][2 * ll + 2],
                  fmaf(w.w, tile[din][2 * ll + 3], acc))));
        }
        pe1c[(size_t)l * 64 + ch] = acc;
    }
}

// ---------------------------------------------------------------------------
// stage1: h1[b][q][ch] (bf16, LN'd — identical values the monolith stored in
// TE1/TO1). Block = (batch b, 64 q). 1 MFMA pass per wave, no q-validity
// clamps (q in [0,2048) by construction), single batch -> small live set.
// Rationale (r15 counters): VALUBusy 24% with dur unchanged vs 41% build ->
// monolith is latency-bound at register-pinned 2 waves/SIMD. Small kernel ->
// HW occupancy follows declared VGPR (r5 mechanism) -> 2-3x latency hiding
// on 60% of the epilogue work, at the cost of a 32MB HBM intermediate.
// ---------------------------------------------------------------------------
__global__ __launch_bounds__(256, 2)
void stage1_kernel(const float* __restrict__ x, const ushort* __restrict__ Wm1,
                   const float* __restrict__ pe1c,
                   const float* __restrict__ W0c, const float* __restrict__ W3c,
                   ushort* __restrict__ h1) {
    const int b = blockIdx.y;
    const int q0 = blockIdx.x * 64;
    const int tid = threadIdx.x;

    __shared__ __align__(16) ushort xs[160];

    // xs[i] = x[2*q0 - 5 + i] (zero-padded): B-frag index 2m+8*quad+j matches
    // the monolith's mapping x = 2q - 5 + 8*quad + j.
    for (int i = tid; i < 160; i += 256) {
        int g = 2 * q0 - 5 + i;
        float v = (g >= 0 && g < 4096) ? x[(size_t)b * 4096 + g] : 0.f;
        xs[i] = f2bf(v);
    }
    __syncthreads();

    const int wv = tid >> 6, lane = tid & 63;
    const int quad = lane >> 4, l15 = lane & 15;
    const int m = wv * 16 + l15;         // 0..63
    const int q = q0 + m;                // always in [0,2048)

    bf16x8 afr1[4];
#pragma unroll
    for (int dt = 0; dt < 4; ++dt)
        afr1[dt] = *(const bf16x8*)&Wm1[((quad * 4 + dt) * 16 + l15) * 8];

    // pe1c rides the MFMA C operand
    f32x4 a1[4];
    {
        const float* pb_ = pe1c + (size_t)q * 64 + quad * 4;
#pragma unroll
        for (int dt = 0; dt < 4; ++dt) {
            float4 pv = *(const float4*)(pb_ + dt * 16);
            a1[dt][0] = pv.x; a1[dt][1] = pv.y; a1[dt][2] = pv.z; a1[dt][3] = pv.w;
        }
    }
    union { bf16x8 v; unsigned u[4]; } tmp;
    {
        const unsigned* p = (const unsigned*)&xs[2 * m + 8 * quad];
#pragma unroll
        for (int i = 0; i < 4; ++i) tmp.u[i] = p[i];
    }
#pragma unroll
    for (int dt = 0; dt < 4; ++dt)
        a1[dt] = __builtin_amdgcn_mfma_f32_16x16x32_bf16(afr1[dt], tmp.v, a1[dt], 0, 0, 0);

    if (q == 0 || q == 2047) {           // conv1 pads emb, not x (rare)
        const float* Wc = (q == 0) ? W0c : W3c;
        const float* xe = x + (size_t)b * 4096 + ((q == 0) ? 0 : 4092);
        float x0 = xe[0], x1 = xe[1], x2 = xe[2], x3 = xe[3];
#pragma unroll
        for (int dt = 0; dt < 4; ++dt)
#pragma unroll
            for (int r = 0; r < 4; ++r) {
                const float* wc = Wc + (dt * 16 + quad * 4 + r) * 4;
                a1[dt][r] -= wc[0] * x0 + wc[1] * x1 + wc[2] * x2 + wc[3] * x3;
            }
    }
    float v[16], s = 0.f, s2 = 0.f;
#pragma unroll
    for (int dt = 0; dt < 4; ++dt)
#pragma unroll
        for (int r = 0; r < 4; ++r) {
            float t = fast_tanh(a1[dt][r]);
            v[dt * 4 + r] = t;
            s += t;
            s2 = fmaf(t, t, s2);
        }
    s += __shfl_xor(s, 16, 64);
    s += __shfl_xor(s, 32, 64);
    s2 += __shfl_xor(s2, 16, 64);
    s2 += __shfl_xor(s2, 32, 64);
    float mean = s * 0.015625f;
    float var = fmaf(-mean, mean, s2 * 0.015625f);
    float rstd = fast_rsqrt(var + LN_EPS);
    float nmr = -mean * rstd;
    ushort* hb = h1 + ((size_t)b * 2048 + q) * 64;
#pragma unroll
    for (int dt = 0; dt < 4; ++dt) {
        bf16x4 pk;
#pragma unroll
        for (int r = 0; r < 4; ++r)
            pk[r] = (short)f2bf(fmaf(v[dt * 4 + r], rstd, nmr));
        *(bf16x4*)(hb + dt * 16 + quad * 4) = pk;
    }
}

// ---------------------------------------------------------------------------
// stage23: mega with stage 1 replaced by a coalesced h1 -> TE1/TO1 LDS fill.
// TE1[r] holds q = 4g0+2r-4 (odd m), TO1[r] holds q = 4g0+2r-3 (even m) —
// same mapping the monolith produced. Out-of-range q -> zeros.
// ---------------------------------------------------------------------------
__global__ __launch_bounds__(256, 2)
void stage23_kernel(const ushort* __restrict__ h1, const ushort* __restrict__ Wm23,
                    const float* __restrict__ cb2t, const float* __restrict__ B2k0,
                    const float* __restrict__ B2k3,
                    const float* __restrict__ cb3t, const float* __restrict__ B3k0,
                    const float* __restrict__ B3k3,
                    float* __restrict__ out) {
    const int b0 = blockIdx.y;               // batches b0 and b0+64
    const int g0 = blockIdx.x * 32;
    const int tid = threadIdx.x;

    __shared__ __align__(16) ushort TE1[2][68][72];
    __shared__ __align__(16) ushort TO1[2][68][72];
    __shared__ __align__(16) ushort TE2[2][34][72];
    __shared__ __align__(16) ushort TO2[2][34][72];

    // ---- fill TE1/TO1 from h1 (8B pieces, 17 iters/thread) ----
    for (int i = tid; i < 2 * 136 * 16; i += 256) {
        int ba = i / 2176, rem = i - ba * 2176;
        int row = rem >> 4, piece = rem & 15;
        ushort* dst;
        int q;
        if (row < 68) { dst = &TE1[ba][row][piece * 4];      q = 4 * g0 + 2 * row - 4; }
        else          { int r2 = row - 68;
                        dst = &TO1[ba][r2][piece * 4];       q = 4 * g0 + 2 * r2 - 3; }
        unsigned long long v = 0ull;
        if (q >= 0 && q < 2048)
            v = *(const unsigned long long*)&h1[((size_t)(b0 + ba * 64) * 2048 + q) * 64 + piece * 4];
        *(unsigned long long*)dst = v;
    }
    __syncthreads();

    const int wv = tid >> 6, lane = tid & 63;
    const int quad = lane >> 4, l15 = lane & 15;

    // ============ stage 2: h2 p = (2g0-1)+n, valid n<66; 5 passes of 16 ====
    {
        f32x4 cfr2[4];
#pragma unroll
        for (int dt = 0; dt < 4; ++dt) {
            float4 cv = *(const float4*)(cb2t + dt * 16 + quad * 4);
            cfr2[dt][0] = cv.x; cfr2[dt][1] = cv.y; cfr2[dt][2] = cv.z; cfr2[dt][3] = cv.w;
        }
        for (int pass = wv; pass < 5; pass += 4) {
            const int n = pass * 16 + l15;
            const int nc = (n < 66) ? n : 65;    // clamp LDS rows in bounds;
            f32x4 a2[2][4];                      // garbage stays in its column
#pragma unroll
            for (int dt = 0; dt < 4; ++dt) { a2[0][dt] = cfr2[dt]; a2[1][dt] = cfr2[dt]; }
#pragma unroll
            for (int kk = 0; kk < 4; ++kk) {
                const int row = nc + ((kk + 1) >> 1);   // kk:0->n 1->n+1 2->n+1 3->n+2
#pragma unroll
                for (int k2 = 0; k2 < 2; ++k2) {
                    bf16x8 bfrA = (kk & 1) ? *(const bf16x8*)&TE1[0][row][k2 * 32 + quad * 8]
                                           : *(const bf16x8*)&TO1[0][row][k2 * 32 + quad * 8];
                    bf16x8 bfrB = (kk & 1) ? *(const bf16x8*)&TE1[1][row][k2 * 32 + quad * 8]
                                           : *(const bf16x8*)&TO1[1][row][k2 * 32 + quad * 8];
                    const ushort* wb = Wm23 + ((((kk * 2 + k2) * 4 + quad) * 4) * 16) * 8;
#pragma unroll
                    for (int dt = 0; dt < 4; ++dt) {
                        bf16x8 afr = *(const bf16x8*)(wb + ((size_t)(dt * 16 + l15)) * 8);
                        a2[0][dt] = __builtin_amdgcn_mfma_f32_16x16x32_bf16(afr, bfrA, a2[0][dt], 0, 0, 0);
                        a2[1][dt] = __builtin_amdgcn_mfma_f32_16x16x32_bf16(afr, bfrB, a2[1][dt], 0, 0, 0);
                    }
                }
            }
            if (n < 66) {
                const int p = 2 * g0 - 1 + n;
                ushort* dstA = (n & 1) ? &TE2[0][(n + 1) >> 1][0] : &TO2[0][n >> 1][0];
                ushort* dstB = (n & 1) ? &TE2[1][(n + 1) >> 1][0] : &TO2[1][n >> 1][0];
                if (p >= 0 && p < 1024) {
                    if (p == 0 || p == 1023) {   // pad taps carry no folded bias
                        const float* Bc = (p == 0) ? B2k0 : B2k3;
#pragma unroll
                        for (int dt = 0; dt < 4; ++dt)
#pragma unroll
                            for (int r = 0; r < 4; ++r) {
                                float bc = Bc[dt * 16 + quad * 4 + r];
                                a2[0][dt][r] -= bc;
                                a2[1][dt][r] -= bc;
                            }
                    }
                    float vA[16], vB[16];
                    float sA = 0.f, s2A = 0.f, sB = 0.f, s2B = 0.f;
#pragma unroll
                    for (int dt = 0; dt < 4; ++dt)
#pragma unroll
                        for (int r = 0; r < 4; ++r) {
                            float ta = fast_tanh(a2[0][dt][r]);
                            float tb = fast_tanh(a2[1][dt][r]);
                            vA[dt * 4 + r] = ta; vB[dt * 4 + r] = tb;
                            sA += ta; s2A = fmaf(ta, ta, s2A);
                            sB += tb; s2B = fmaf(tb, tb, s2B);
                        }
                    sA += __shfl_xor(sA, 16, 64);  sB += __shfl_xor(sB, 16, 64);
                    s2A += __shfl_xor(s2A, 16, 64); s2B += __shfl_xor(s2B, 16, 64);
                    sA += __shfl_xor(sA, 32, 64);  sB += __shfl_xor(sB, 32, 64);
                    s2A += __shfl_xor(s2A, 32, 64); s2B += __shfl_xor(s2B, 32, 64);
                    float meanA = sA * 0.015625f, meanB = sB * 0.015625f;
                    float varA = fmaf(-meanA, meanA, s2A * 0.015625f);
                    float varB = fmaf(-meanB, meanB, s2B * 0.015625f);
                    float rstdA = fast_rsqrt(varA + LN_EPS), rstdB = fast_rsqrt(varB + LN_EPS);
                    float nmrA = -meanA * rstdA, nmrB = -meanB * rstdB;
#pragma unroll
                    for (int dt = 0; dt < 4; ++dt) {
                        bf16x4 pkA, pkB;
#pragma unroll
                        for (int r = 0; r < 4; ++r) {
                            pkA[r] = (short)f2bf(fmaf(vA[dt * 4 + r], rstdA, nmrA));
                            pkB[r] = (short)f2bf(fmaf(vB[dt * 4 + r], rstdB, nmrB));
                        }
                        *(bf16x4*)(dstA + dt * 16 + quad * 4) = pkA;
                        *(bf16x4*)(dstB + dt * 16 + quad * 4) = pkB;
                    }
                } else {
                    bf16x4 z; z[0] = 0; z[1] = 0; z[2] = 0; z[3] = 0;
#pragma unroll
                    for (int dt = 0; dt < 4; ++dt) {
                        *(bf16x4*)(dstA + dt * 16 + quad * 4) = z;
                        *(bf16x4*)(dstB + dt * 16 + quad * 4) = z;
                    }
                }
            }
        }
    }
    __syncthreads();

    // ============ stage 3: l = g0 + m3; m3-half by wv&1, dt-pair by wv>>1 ==
    {
        const int m3 = (wv & 1) * 16 + l15;
        const int dth = wv >> 1;                 // 0,1 -> dt{0,1}; 2,3 -> dt{2,3}
        f32x4 a3[2][2];
#pragma unroll
        for (int d2 = 0; d2 < 2; ++d2) {
            float4 cv = *(const float4*)(cb3t + (dth * 2 + d2) * 16 + quad * 4);
            f32x4 c; c[0] = cv.x; c[1] = cv.y; c[2] = cv.z; c[3] = cv.w;
            a3[0][d2] = c; a3[1][d2] = c;
        }
        const ushort* Wg3 = Wm23 + 16384;
#pragma unroll
        for (int kk = 0; kk < 4; ++kk) {
            const int row = m3 + ((kk + 1) >> 1);
#pragma unroll
            for (int k2 = 0; k2 < 2; ++k2) {
                bf16x8 bfrA = (kk & 1) ? *(const bf16x8*)&TE2[0][row][k2 * 32 + quad * 8]
                                       : *(const bf16x8*)&TO2[0][row][k2 * 32 + quad * 8];
                bf16x8 bfrB = (kk & 1) ? *(const bf16x8*)&TE2[1][row][k2 * 32 + quad * 8]
                                       : *(const bf16x8*)&TO2[1][row][k2 * 32 + quad * 8];
                const ushort* wb = Wg3 + ((((kk * 2 + k2) * 4 + quad) * 4) * 16) * 8;
#pragma unroll
                for (int d2 = 0; d2 < 2; ++d2) {
                    const int dt = dth * 2 + d2;
                    bf16x8 afr = *(const bf16x8*)(wb + ((size_t)(dt * 16 + l15)) * 8);
                    a3[0][d2] = __builtin_amdgcn_mfma_f32_16x16x32_bf16(afr, bfrA, a3[0][d2], 0, 0, 0);
                    a3[1][d2] = __builtin_amdgcn_mfma_f32_16x16x32_bf16(afr, bfrB, a3[1][d2], 0, 0, 0);
                }
            }
        }
        const int l = g0 + m3;
        if (l == 0 || l == 511) {                // pad taps carry no folded bias
            const float* Bc = (l == 0) ? B3k0 : B3k3;
#pragma unroll
            for (int ba = 0; ba < 2; ++ba)
#pragma unroll
                for (int d2 = 0; d2 < 2; ++d2)
#pragma unroll
                    for (int r = 0; r < 4; ++r)
                        a3[ba][d2][r] -= Bc[(dth * 2 + d2) * 16 + quad * 4 + r];
        }
#pragma unroll
        for (int ba = 0; ba < 2; ++ba) {
            float* ob = out + ((size_t)((b0 + ba * 64) * 512) + l) * 64;
#pragma unroll
            for (int d2 = 0; d2 < 2; ++d2) {
                const int dt = dth * 2 + d2;
                float4 st = make_float4(fast_tanh(a3[ba][d2][0]),
                                        fast_tanh(a3[ba][d2][1]),
                                        fast_tanh(a3[ba][d2][2]),
                                        fast_tanh(a3[ba][d2][3]));
                *(float4*)(ob + dt * 16 + quad * 4) = st;
            }
        }
    }
}

extern "C" void kernel_launch(void* const* d_in, const int* in_sizes, int n_in,
                              void* d_out, int out_size, void* d_ws, size_t ws_size,
                              hipStream_t stream) {
    (void)in_sizes; (void)n_in; (void)out_size; (void)ws_size;
    const float* x   = (const float*)d_in[0];
    const float* w3  = (const float*)d_in[1];
    const float* b3  = (const float*)d_in[2];
    const float* w5  = (const float*)d_in[3];
    const float* b5  = (const float*)d_in[4];
    const float* w7  = (const float*)d_in[5];
    const float* b7  = (const float*)d_in[6];
    const float* w9  = (const float*)d_in[7];
    const float* b9  = (const float*)d_in[8];
    const float* cw1 = (const float*)d_in[9];
    const float* cb1 = (const float*)d_in[10];
    const float* cw2 = (const float*)d_in[11];
    const float* cb2 = (const float*)d_in[12];
    const float* cw3 = (const float*)d_in[13];
    const float* cb3 = (const float*)d_in[14];
    const float* lg1 = (const float*)d_in[15];
    const float* lb1 = (const float*)d_in[16];
    const float* lg2 = (const float*)d_in[17];
    const float* lb2 = (const float*)d_in[18];
    float* out = (float*)d_out;

    // ws layout (bytes):
    char* w = (char*)d_ws;
    ushort* Wm23 = (ushort*)(w + 0);          //  65536 B (2 x 16384 bf16, lg-folded)
    ushort* Wm1  = (ushort*)(w + 65536);      //   4096 B (2048 bf16)
    float*  W0c  = (float*)(w + 69632);       //   1024 B
    float*  W3c  = (float*)(w + 70656);       //   1024 B
    float*  cb2t = (float*)(w + 71680);       //    256 B
    float*  B2k0 = (float*)(w + 71936);       //    256 B
    float*  B2k3 = (float*)(w + 72192);       //    256 B
    float*  cb3t = (float*)(w + 72448);       //    256 B
    float*  B3k0 = (float*)(w + 72704);       //    256 B
    float*  B3k3 = (float*)(w + 72960);       //    256 B
    float*  pe1c = (float*)(w + 73216);       // 524288 B (2048 x 64 fp32)
    ushort* h1   = (ushort*)(w + 1048576);    // 33554432 B (128 x 2048 x 64 bf16)

    prep_kernel<<<512, 256, 0, stream>>>(cw1, cw2, cw3, w3, b3, w5, b5, w7, b7, w9, b9,
                                         cb1, cb2, cb3, lg1, lb1, lg2, lb2,
                                         Wm23, Wm1, W0c, W3c, pe1c,
                                         cb2t, B2k0, B2k3, cb3t, B3k0, B3k3);
    stage1_kernel<<<dim3(32, BATCH), 256, 0, stream>>>(x, Wm1, pe1c, W0c, W3c, h1);
    stage23_kernel<<<dim3(16, BATCH / 2), 256, 0, stream>>>(
        h1, Wm23, cb2t, B2k0, B2k3, cb3t, B3k0, B3k3, out);
}

// Round 17
// 141.676 us; speedup vs baseline: 1.1775x; 1.1775x over previous
//
#include <hip/hip_runtime.h>
#include <math.h>

#define BATCH 128
#define LN_EPS 1e-5f

typedef short bf16x8 __attribute__((ext_vector_type(8)));
typedef short bf16x4 __attribute__((ext_vector_type(4)));
typedef float f32x4  __attribute__((ext_vector_type(4)));

__device__ __forceinline__ ushort f2bf(float f) {
    // native RNE conversion -> compiler emits v_cvt_pk_bf16_f32 for pairs
    return __builtin_bit_cast(ushort, (__bf16)f);
}

// tanh via fast exp + HW-approx reciprocal. Default hipcc (-O3, no fast-math)
// lowers `2.f/(e+1.f)` to the ~9-instr IEEE div sequence; v_rcp_f32 is ~1ulp
// and the result is immediately bf16-rounded, so the approx is numerically
// free. r13 A/B: -9.4us total.
__device__ __forceinline__ float fast_tanh(float v) {
    float e = __expf(2.f * v);
    float r = __builtin_amdgcn_rcpf(e + 1.f);
    return fmaf(-2.f, r, 1.f);
}

__device__ __forceinline__ float fast_rsqrt(float v) {
    return __builtin_amdgcn_rsqf(v);      // vs OCML precise rsqrt expansion
}

// ---------------------------------------------------------------------------
// prep v2 — 512 blocks, folded-bias PE tile (round 11).
// ---------------------------------------------------------------------------
__global__ __launch_bounds__(256, 2)
void prep_kernel(const float* __restrict__ cw1, const float* __restrict__ cw2,
                 const float* __restrict__ cw3,
                 const float* __restrict__ w3, const float* __restrict__ b3,
                 const float* __restrict__ w5, const float* __restrict__ b5,
                 const float* __restrict__ w7, const float* __restrict__ b7,
                 const float* __restrict__ w9, const float* __restrict__ b9,
                 const float* __restrict__ cb1, const float* __restrict__ cb2,
                 const float* __restrict__ cb3,
                 const float* __restrict__ lg1, const float* __restrict__ lb1,
                 const float* __restrict__ lg2, const float* __restrict__ lb2,
                 ushort* __restrict__ Wm23, ushort* __restrict__ Wm1,
                 float* __restrict__ W0c, float* __restrict__ W3c,
                 float* __restrict__ pe1c,
                 float* __restrict__ cb2t, float* __restrict__ B2k0,
                 float* __restrict__ B2k3,
                 float* __restrict__ cb3t, float* __restrict__ B3k0,
                 float* __restrict__ B3k3) {
    const int tid = threadIdx.x;
    const int bx  = blockIdx.x;              // 512 blocks

    __shared__ float tile[64][12];           // PE+bias window (10 cols used)
    __shared__ float red[4][64][24];         // block-0 composite partials

    // ---- Wm23 bf16 A-frags (tap-split layout), lg-folded: 64 elems/block --
    if (tid < 64) {
        int idx = bx * 64 + tid;             // 0 .. 32767 exactly
        int s = idx >> 14, r = idx & 16383;
        int j = r & 7, l15 = (r >> 3) & 15, dt = (r >> 7) & 3;
        int quad = (r >> 9) & 3, k2 = (r >> 11) & 1, kk = (r >> 12) & 3;
        int dout = dt * 16 + l15, din = k2 * 32 + quad * 8 + j;
        const float* cw = (s == 0) ? cw2 : cw3;
        const float* lg = (s == 0) ? lg1 : lg2;
        Wm23[idx] = f2bf(cw[dout * 256 + din * 4 + kk] * lg[din]);
    }

    // ---- block 1: bias folds for conv2(b1) and conv3(b2) ----
    if (bx == 1 && tid < 128) {
        const int s = tid >> 6, ch = tid & 63;
        const float* cw = (s == 0) ? cw2 : cw3;
        const float* lb = (s == 0) ? lb1 : lb2;
        float full = 0.f, k0 = 0.f, k3 = 0.f;
        for (int din = 0; din < 64; ++din) {
            float bv = lb[din];
            const float* wr = cw + ch * 256 + din * 4;
            k0 = fmaf(wr[0], bv, k0);
            k3 = fmaf(wr[3], bv, k3);
            full = fmaf(wr[0] + wr[1] + wr[2] + wr[3], bv, full);
        }
        if (s == 0) { cb2t[ch] = cb2[ch] + full; B2k0[ch] = k0; B2k3[ch] = k3; }
        else        { cb3t[ch] = cb3[ch] + full; B3k0[ch] = k0; B3k3[ch] = k3; }
    }

    // ---- block 0: composite weights, din-split 4 ways ----
    if (bx == 0) {
        const int ch = tid & 63, part = tid >> 6;
        const float* cw1row = cw1 + ch * 256;
        float acc[24];                        // [0..11]=weff [16..19]=w0c [20..23]=w3c
#pragma unroll
        for (int j = 0; j < 24; ++j) acc[j] = 0.f;
        for (int din = part * 16; din < part * 16 + 16; ++din) {
            int ki = din & 3, g = din >> 2;
            float wl[9];
#pragma unroll
            for (int j = 0; j < 9; ++j) wl[j] = 0.f;
            if (ki == 0)      { for (int j = 0; j < 3; ++j) wl[3 + j] = w3[g * 3 + j]; }
            else if (ki == 1) { for (int j = 0; j < 5; ++j) wl[2 + j] = w5[g * 5 + j]; }
            else if (ki == 2) { for (int j = 0; j < 7; ++j) wl[1 + j] = w7[g * 7 + j]; }
            else              { for (int j = 0; j < 9; ++j) wl[j]     = w9[g * 9 + j]; }
#pragma unroll
            for (int kk = 0; kk < 4; ++kk) {
                float c = cw1row[din * 4 + kk];
#pragma unroll
                for (int u = 0; u < 9; ++u) acc[kk + u] += c * wl[u];
            }
            float c0 = cw1row[din * 4 + 0], c3 = cw1row[din * 4 + 3];
#pragma unroll
            for (int u = 0; u < 4; ++u) { acc[16 + u] += c0 * wl[5 + u]; acc[20 + u] += c3 * wl[u]; }
        }
#pragma unroll
        for (int j = 0; j < 24; ++j) red[part][ch][j] = acc[j];
    }

    // ---- PE+bias tile: tile[d][pp], p = 8*bx - 1 + pp, pp < 10 ----
    for (int i = tid; i < 320; i += 256) {
        int d2 = i / 10, pp = i - d2 * 10;
        int p = 8 * bx - 1 + pp;
        int din0 = 2 * d2, g = d2 >> 1;
        float sv = 0.f, cv = 0.f;
        if (p >= 0 && p < 4096) {
            float dv = __expf((float)din0 * -0.14391156831212787f);  // -ln(1e4)/64
            float s, c;
            __sincosf((float)p * dv, &s, &c);
            bool lo = (din0 & 3) == 0;
            sv = s + (lo ? b3[g] : b7[g]);
            cv = c + (lo ? b5[g] : b9[g]);
        }
        tile[din0][pp] = sv;
        tile[din0 + 1][pp] = cv;
    }
    __syncthreads();

    // ---- block 0 finalize composite weights ----
    if (bx == 0 && tid < 64) {
        const int ch = tid;
        float w24[24];
#pragma unroll
        for (int j = 0; j < 24; ++j)
            w24[j] = red[0][ch][j] + red[1][ch][j] + red[2][ch][j] + red[3][ch][j];
        int dt = ch >> 4, l15 = ch & 15;
#pragma unroll
        for (int quad = 0; quad < 4; ++quad)
#pragma unroll
            for (int j = 0; j < 8; ++j) {
                int k = quad * 8 + j;
                Wm1[((quad * 4 + dt) * 16 + l15) * 8 + j] = f2bf(k < 12 ? w24[k] : 0.f);
            }
#pragma unroll
        for (int u = 0; u < 4; ++u) { W0c[ch * 4 + u] = w24[16 + u]; W3c[ch * 4 + u] = w24[20 + u]; }
    }

    // ---- pe1c[l][ch]: l = bx*4 + (tid>>6), ch = tid&63 ----
    {
        const int ll = tid >> 6, ch = tid & 63;
        const int l = bx * 4 + ll;
        float acc = cb1[ch];
        const float* cwr = cw1 + ch * 256;
        for (int din = 0; din < 64; ++din) {
            float4 w = *(const float4*)(cwr + din * 4);
            acc = fmaf(w.x, tile[din][2 * ll + 0],
                  fmaf(w.y, tile[din][2 * ll + 1],
                  fmaf(w.z, tile[din][2 * ll + 2],
                  fmaf(w.w, tile[din][2 * ll + 3], acc))));
        }
        pe1c[(size_t)l * 64 + ch] = acc;
    }
}

// ---------------------------------------------------------------------------
// Batch-paired mega (round-15 configuration — best verified: 143.2us total,
// mega 44.5us, VGPR 112, zero spill). Session bounds:
//  - occupancy register-pinned at 2 waves/SIMD (5 spill datapoints: any
//    launch-bounds >2, persistence r14, all spill at the 128-reg cliff);
//  - VALU cut 41%->24% with dur unchanged -> latency-bound, more op cuts
//    can't pay;
//  - kernel fission (r16) loses: 64MB HBM detour + exposed LDS fill > the
//    occupancy gain;
//  - the ~106us total-minus-kernels gap is harness-fixed (poison fills
//    measured at 74-81% HBM BW, 42-45us each).
// ---------------------------------------------------------------------------
__global__ __launch_bounds__(256, 2)
void mega_kernel(const float* __restrict__ x,
                 const ushort* __restrict__ Wm1, const ushort* __restrict__ Wm23,
                 const float* __restrict__ pe1c,
                 const float* __restrict__ W0c, const float* __restrict__ W3c,
                 const float* __restrict__ cb2t, const float* __restrict__ B2k0,
                 const float* __restrict__ B2k3,
                 const float* __restrict__ cb3t, const float* __restrict__ B3k0,
                 const float* __restrict__ B3k3,
                 float* __restrict__ out) {
    const int b0 = blockIdx.y;               // batches b0 and b0+64
    const int g0 = blockIdx.x * 32;
    const int tid = threadIdx.x;

    __shared__ __align__(16) ushort xs[2][320];
    __shared__ __align__(16) ushort TE1[2][68][72];
    __shared__ __align__(16) ushort TO1[2][68][72];
    __shared__ __align__(16) ushort TE2[2][34][72];
    __shared__ __align__(16) ushort TO2[2][34][72];

    // ---- x windows -> bf16 LDS: xs[ba][i] = x[b0+ba*64][8*g0 - 11 + i] ----
    for (int i = tid; i < 640; i += 256) {
        int ba = (i >= 320) ? 1 : 0, j = i - ba * 320;
        int g = 8 * g0 - 11 + j;
        float v = (g >= 0 && g < 4096) ? x[(size_t)(b0 + ba * 64) * 4096 + g] : 0.f;
        xs[ba][j] = f2bf(v);
    }
    __syncthreads();

    const int wv = tid >> 6, lane = tid & 63;
    const int quad = lane >> 4, l15 = lane & 15;

    // ============ stage 1: h1 q = (4g0-3)+m, valid m<134; 9 passes of 16 ===
    {
        bf16x8 afr1[4];
#pragma unroll
        for (int dt = 0; dt < 4; ++dt)
            afr1[dt] = *(const bf16x8*)&Wm1[((quad * 4 + dt) * 16 + l15) * 8];
        const int qstart = 4 * g0 - 3;

        // rotating prefetch state for {pe1c C-operand, xs B-fragments}
        float4 pv[4];
        unsigned xA[4], xB[4];
        {   // prefetch first pass (wv < 4 < 9 always)
            const int m = wv * 16 + l15;
            const int q = qstart + m;
            const int qc = (q < 0) ? 0 : ((q > 2047) ? 2047 : q);
            const float* pb_ = pe1c + (size_t)qc * 64 + quad * 4;
#pragma unroll
            for (int dt = 0; dt < 4; ++dt) pv[dt] = *(const float4*)(pb_ + dt * 16);
            const unsigned* pA = (const unsigned*)&xs[0][2 * m + 8 * quad];
            const unsigned* pB = (const unsigned*)&xs[1][2 * m + 8 * quad];
#pragma unroll
            for (int i = 0; i < 4; ++i) { xA[i] = pA[i]; xB[i] = pB[i]; }
        }
        for (int pass = wv; pass < 9; pass += 4) {
            const int m = pass * 16 + l15;
            const int q = qstart + m;
            union { bf16x8 v; unsigned u[4]; } tA, tB;
#pragma unroll
            for (int i = 0; i < 4; ++i) { tA.u[i] = xA[i]; tB.u[i] = xB[i]; }
            f32x4 a1[2][4];
#pragma unroll
            for (int dt = 0; dt < 4; ++dt) {
                f32x4 c;
                c[0] = pv[dt].x; c[1] = pv[dt].y; c[2] = pv[dt].z; c[3] = pv[dt].w;
                a1[0][dt] = __builtin_amdgcn_mfma_f32_16x16x32_bf16(afr1[dt], tA.v, c, 0, 0, 0);
                a1[1][dt] = __builtin_amdgcn_mfma_f32_16x16x32_bf16(afr1[dt], tB.v, c, 0, 0, 0);
            }
            // ---- prefetch pass+4 BEFORE the epilogue (hide VMEM+LDS) ----
            if (pass + 4 < 9) {
                const int m2 = m + 64;
                const int q2 = q + 64;
                const int qc2 = (q2 < 0) ? 0 : ((q2 > 2047) ? 2047 : q2);
                const float* pb2 = pe1c + (size_t)qc2 * 64 + quad * 4;
#pragma unroll
                for (int dt = 0; dt < 4; ++dt) pv[dt] = *(const float4*)(pb2 + dt * 16);
                const unsigned* pA2 = (const unsigned*)&xs[0][2 * m2 + 8 * quad];
                const unsigned* pB2 = (const unsigned*)&xs[1][2 * m2 + 8 * quad];
#pragma unroll
                for (int i = 0; i < 4; ++i) { xA[i] = pA2[i]; xB[i] = pB2[i]; }
            }
            // ---- joint A/B epilogue ----
            if (m < 134) {                       // shfl partners share m
                ushort* dstA = (m & 1) ? &TE1[0][(m + 1) >> 1][0] : &TO1[0][m >> 1][0];
                ushort* dstB = (m & 1) ? &TE1[1][(m + 1) >> 1][0] : &TO1[1][m >> 1][0];
                if (q >= 0 && q < 2048) {
                    if (q == 0 || q == 2047) {   // conv1 pads emb, not x (rare)
                        const float* Wc = (q == 0) ? W0c : W3c;
#pragma unroll
                        for (int ba = 0; ba < 2; ++ba) {
                            const float* xe = x + (size_t)(b0 + ba * 64) * 4096
                                                + ((q == 0) ? 0 : 4092);
                            float x0 = xe[0], x1 = xe[1], x2 = xe[2], x3 = xe[3];
#pragma unroll
                            for (int dt = 0; dt < 4; ++dt)
#pragma unroll
                                for (int r = 0; r < 4; ++r) {
                                    const float* wc = Wc + (dt * 16 + quad * 4 + r) * 4;
                                    a1[ba][dt][r] -= wc[0] * x0 + wc[1] * x1 + wc[2] * x2 + wc[3] * x3;
                                }
                        }
                    }
                    float vA[16], vB[16];
                    float sA = 0.f, s2A = 0.f, sB = 0.f, s2B = 0.f;
#pragma unroll
                    for (int dt = 0; dt < 4; ++dt)
#pragma unroll
                        for (int r = 0; r < 4; ++r) {
                            float ta = fast_tanh(a1[0][dt][r]);
                            float tb = fast_tanh(a1[1][dt][r]);
                            vA[dt * 4 + r] = ta; vB[dt * 4 + r] = tb;
                            sA += ta; s2A = fmaf(ta, ta, s2A);
                            sB += tb; s2B = fmaf(tb, tb, s2B);
                        }
                    sA += __shfl_xor(sA, 16, 64);  sB += __shfl_xor(sB, 16, 64);
                    s2A += __shfl_xor(s2A, 16, 64); s2B += __shfl_xor(s2B, 16, 64);
                    sA += __shfl_xor(sA, 32, 64);  sB += __shfl_xor(sB, 32, 64);
                    s2A += __shfl_xor(s2A, 32, 64); s2B += __shfl_xor(s2B, 32, 64);
                    float meanA = sA * 0.015625f, meanB = sB * 0.015625f;
                    float varA = fmaf(-meanA, meanA, s2A * 0.015625f);
                    float varB = fmaf(-meanB, meanB, s2B * 0.015625f);
                    float rstdA = fast_rsqrt(varA + LN_EPS), rstdB = fast_rsqrt(varB + LN_EPS);
                    float nmrA = -meanA * rstdA, nmrB = -meanB * rstdB;
#pragma unroll
                    for (int dt = 0; dt < 4; ++dt) {
                        bf16x4 pkA, pkB;
#pragma unroll
                        for (int r = 0; r < 4; ++r) {
                            pkA[r] = (short)f2bf(fmaf(vA[dt * 4 + r], rstdA, nmrA));
                            pkB[r] = (short)f2bf(fmaf(vB[dt * 4 + r], rstdB, nmrB));
                        }
                        *(bf16x4*)(dstA + dt * 16 + quad * 4) = pkA;
                        *(bf16x4*)(dstB + dt * 16 + quad * 4) = pkB;
                    }
                } else {
                    bf16x4 z; z[0] = 0; z[1] = 0; z[2] = 0; z[3] = 0;
#pragma unroll
                    for (int dt = 0; dt < 4; ++dt) {
                        *(bf16x4*)(dstA + dt * 16 + quad * 4) = z;
                        *(bf16x4*)(dstB + dt * 16 + quad * 4) = z;
                    }
                }
            }
        }
    }
    __syncthreads();

    // ============ stage 2: h2 p = (2g0-1)+n, valid n<66; 5 passes of 16 ====
    {
        f32x4 cfr2[4];                           // pass-invariant C-init, hoisted
#pragma unroll
        for (int dt = 0; dt < 4; ++dt) {
            float4 cv = *(const float4*)(cb2t + dt * 16 + quad * 4);
            cfr2[dt][0] = cv.x; cfr2[dt][1] = cv.y; cfr2[dt][2] = cv.z; cfr2[dt][3] = cv.w;
        }
        for (int pass = wv; pass < 5; pass += 4) {
            const int n = pass * 16 + l15;
            const int nc = (n < 66) ? n : 65;    // clamp LDS rows in bounds;
            f32x4 a2[2][4];                      // garbage stays in its column
#pragma unroll
            for (int dt = 0; dt < 4; ++dt) { a2[0][dt] = cfr2[dt]; a2[1][dt] = cfr2[dt]; }
#pragma unroll
            for (int kk = 0; kk < 4; ++kk) {
                const int row = nc + ((kk + 1) >> 1);   // kk:0->n 1->n+1 2->n+1 3->n+2
#pragma unroll
                for (int k2 = 0; k2 < 2; ++k2) {
                    bf16x8 bfrA = (kk & 1) ? *(const bf16x8*)&TE1[0][row][k2 * 32 + quad * 8]
                                           : *(const bf16x8*)&TO1[0][row][k2 * 32 + quad * 8];
                    bf16x8 bfrB = (kk & 1) ? *(const bf16x8*)&TE1[1][row][k2 * 32 + quad * 8]
                                           : *(const bf16x8*)&TO1[1][row][k2 * 32 + quad * 8];
                    const ushort* wb = Wm23 + ((((kk * 2 + k2) * 4 + quad) * 4) * 16) * 8;
#pragma unroll
                    for (int dt = 0; dt < 4; ++dt) {
                        bf16x8 afr = *(const bf16x8*)(wb + ((size_t)(dt * 16 + l15)) * 8);
                        a2[0][dt] = __builtin_amdgcn_mfma_f32_16x16x32_bf16(afr, bfrA, a2[0][dt], 0, 0, 0);
                        a2[1][dt] = __builtin_amdgcn_mfma_f32_16x16x32_bf16(afr, bfrB, a2[1][dt], 0, 0, 0);
                    }
                }
            }
            if (n < 66) {
                const int p = 2 * g0 - 1 + n;
                ushort* dstA = (n & 1) ? &TE2[0][(n + 1) >> 1][0] : &TO2[0][n >> 1][0];
                ushort* dstB = (n & 1) ? &TE2[1][(n + 1) >> 1][0] : &TO2[1][n >> 1][0];
                if (p >= 0 && p < 1024) {
                    if (p == 0 || p == 1023) {   // pad taps carry no folded bias
                        const float* Bc = (p == 0) ? B2k0 : B2k3;
#pragma unroll
                        for (int dt = 0; dt < 4; ++dt)
#pragma unroll
                            for (int r = 0; r < 4; ++r) {
                                float bc = Bc[dt * 16 + quad * 4 + r];
                                a2[0][dt][r] -= bc;
                                a2[1][dt][r] -= bc;
                            }
                    }
                    float vA[16], vB[16];
                    float sA = 0.f, s2A = 0.f, sB = 0.f, s2B = 0.f;
#pragma unroll
                    for (int dt = 0; dt < 4; ++dt)
#pragma unroll
                        for (int r = 0; r < 4; ++r) {
                            float ta = fast_tanh(a2[0][dt][r]);
                            float tb = fast_tanh(a2[1][dt][r]);
                            vA[dt * 4 + r] = ta; vB[dt * 4 + r] = tb;
                            sA += ta; s2A = fmaf(ta, ta, s2A);
                            sB += tb; s2B = fmaf(tb, tb, s2B);
                        }
                    sA += __shfl_xor(sA, 16, 64);  sB += __shfl_xor(sB, 16, 64);
                    s2A += __shfl_xor(s2A, 16, 64); s2B += __shfl_xor(s2B, 16, 64);
                    sA += __shfl_xor(sA, 32, 64);  sB += __shfl_xor(sB, 32, 64);
                    s2A += __shfl_xor(s2A, 32, 64); s2B += __shfl_xor(s2B, 32, 64);
                    float meanA = sA * 0.015625f, meanB = sB * 0.015625f;
                    float varA = fmaf(-meanA, meanA, s2A * 0.015625f);
                    float varB = fmaf(-meanB, meanB, s2B * 0.015625f);
                    float rstdA = fast_rsqrt(varA + LN_EPS), rstdB = fast_rsqrt(varB + LN_EPS);
                    float nmrA = -meanA * rstdA, nmrB = -meanB * rstdB;
#pragma unroll
                    for (int dt = 0; dt < 4; ++dt) {
                        bf16x4 pkA, pkB;
#pragma unroll
                        for (int r = 0; r < 4; ++r) {
                            pkA[r] = (short)f2bf(fmaf(vA[dt * 4 + r], rstdA, nmrA));
                            pkB[r] = (short)f2bf(fmaf(vB[dt * 4 + r], rstdB, nmrB));
                        }
                        *(bf16x4*)(dstA + dt * 16 + quad * 4) = pkA;
                        *(bf16x4*)(dstB + dt * 16 + quad * 4) = pkB;
                    }
                } else {
                    bf16x4 z; z[0] = 0; z[1] = 0; z[2] = 0; z[3] = 0;
#pragma unroll
                    for (int dt = 0; dt < 4; ++dt) {
                        *(bf16x4*)(dstA + dt * 16 + quad * 4) = z;
                        *(bf16x4*)(dstB + dt * 16 + quad * 4) = z;
                    }
                }
            }
        }
    }
    __syncthreads();

    // ============ stage 3: l = g0 + m3; m3-half by wv&1, dt-pair by wv>>1 ==
    {
        const int m3 = (wv & 1) * 16 + l15;
        const int dth = wv >> 1;                 // 0,1 -> dt{0,1}; 2,3 -> dt{2,3}
        f32x4 a3[2][2];
#pragma unroll
        for (int d2 = 0; d2 < 2; ++d2) {
            float4 cv = *(const float4*)(cb3t + (dth * 2 + d2) * 16 + quad * 4);
            f32x4 c; c[0] = cv.x; c[1] = cv.y; c[2] = cv.z; c[3] = cv.w;
            a3[0][d2] = c; a3[1][d2] = c;
        }
        const ushort* Wg3 = Wm23 + 16384;
#pragma unroll
        for (int kk = 0; kk < 4; ++kk) {
            const int row = m3 + ((kk + 1) >> 1);
#pragma unroll
            for (int k2 = 0; k2 < 2; ++k2) {
                bf16x8 bfrA = (kk & 1) ? *(const bf16x8*)&TE2[0][row][k2 * 32 + quad * 8]
                                       : *(const bf16x8*)&TO2[0][row][k2 * 32 + quad * 8];
                bf16x8 bfrB = (kk & 1) ? *(const bf16x8*)&TE2[1][row][k2 * 32 + quad * 8]
                                       : *(const bf16x8*)&TO2[1][row][k2 * 32 + quad * 8];
                const ushort* wb = Wg3 + ((((kk * 2 + k2) * 4 + quad) * 4) * 16) * 8;
#pragma unroll
                for (int d2 = 0; d2 < 2; ++d2) {
                    const int dt = dth * 2 + d2;
                    bf16x8 afr = *(const bf16x8*)(wb + ((size_t)(dt * 16 + l15)) * 8);
                    a3[0][d2] = __builtin_amdgcn_mfma_f32_16x16x32_bf16(afr, bfrA, a3[0][d2], 0, 0, 0);
                    a3[1][d2] = __builtin_amdgcn_mfma_f32_16x16x32_bf16(afr, bfrB, a3[1][d2], 0, 0, 0);
                }
            }
        }
        const int l = g0 + m3;
        if (l == 0 || l == 511) {                // pad taps carry no folded bias
            const float* Bc = (l == 0) ? B3k0 : B3k3;
#pragma unroll
            for (int ba = 0; ba < 2; ++ba)
#pragma unroll
                for (int d2 = 0; d2 < 2; ++d2)
#pragma unroll
                    for (int r = 0; r < 4; ++r)
                        a3[ba][d2][r] -= Bc[(dth * 2 + d2) * 16 + quad * 4 + r];
        }
#pragma unroll
        for (int ba = 0; ba < 2; ++ba) {
            float* ob = out + ((size_t)((b0 + ba * 64) * 512) + l) * 64;
#pragma unroll
            for (int d2 = 0; d2 < 2; ++d2) {
                const int dt = dth * 2 + d2;
                float4 st = make_float4(fast_tanh(a3[ba][d2][0]),
                                        fast_tanh(a3[ba][d2][1]),
                                        fast_tanh(a3[ba][d2][2]),
                                        fast_tanh(a3[ba][d2][3]));
                *(float4*)(ob + dt * 16 + quad * 4) = st;
            }
        }
    }
}

extern "C" void kernel_launch(void* const* d_in, const int* in_sizes, int n_in,
                              void* d_out, int out_size, void* d_ws, size_t ws_size,
                              hipStream_t stream) {
    (void)in_sizes; (void)n_in; (void)out_size; (void)ws_size;
    const float* x   = (const float*)d_in[0];
    const float* w3  = (const float*)d_in[1];
    const float* b3  = (const float*)d_in[2];
    const float* w5  = (const float*)d_in[3];
    const float* b5  = (const float*)d_in[4];
    const float* w7  = (const float*)d_in[5];
    const float* b7  = (const float*)d_in[6];
    const float* w9  = (const float*)d_in[7];
    const float* b9  = (const float*)d_in[8];
    const float* cw1 = (const float*)d_in[9];
    const float* cb1 = (const float*)d_in[10];
    const float* cw2 = (const float*)d_in[11];
    const float* cb2 = (const float*)d_in[12];
    const float* cw3 = (const float*)d_in[13];
    const float* cb3 = (const float*)d_in[14];
    const float* lg1 = (const float*)d_in[15];
    const float* lb1 = (const float*)d_in[16];
    const float* lg2 = (const float*)d_in[17];
    const float* lb2 = (const float*)d_in[18];
    float* out = (float*)d_out;

    // ws layout (bytes):
    char* w = (char*)d_ws;
    ushort* Wm23 = (ushort*)(w + 0);          //  65536 B (2 x 16384 bf16, lg-folded)
    ushort* Wm1  = (ushort*)(w + 65536);      //   4096 B (2048 bf16)
    float*  W0c  = (float*)(w + 69632);       //   1024 B
    float*  W3c  = (float*)(w + 70656);       //   1024 B
    float*  cb2t = (float*)(w + 71680);       //    256 B
    float*  B2k0 = (float*)(w + 71936);       //    256 B
    float*  B2k3 = (float*)(w + 72192);       //    256 B
    float*  cb3t = (float*)(w + 72448);       //    256 B
    float*  B3k0 = (float*)(w + 72704);       //    256 B
    float*  B3k3 = (float*)(w + 72960);       //    256 B
    float*  pe1c = (float*)(w + 73216);       // 524288 B (2048 x 64 fp32)

    prep_kernel<<<512, 256, 0, stream>>>(cw1, cw2, cw3, w3, b3, w5, b5, w7, b7, w9, b9,
                                         cb1, cb2, cb3, lg1, lb1, lg2, lb2,
                                         Wm23, Wm1, W0c, W3c, pe1c,
                                         cb2t, B2k0, B2k3, cb3t, B3k0, B3k3);
    mega_kernel<<<dim3(16, BATCH / 2), 256, 0, stream>>>(
        x, Wm1, Wm23, pe1c, W0c, W3c, cb2t, B2k0, B2k3, cb3t, B3k0, B3k3, out);
}